// Round 1
// baseline (766.984 us; speedup 1.0000x reference)
//
#include <hip/hip_runtime.h>

#define Nn 512
#define Cc 128
#define NRr (Nn*Nn)

typedef __attribute__((ext_vector_type(8))) _Float16 h8;
typedef __attribute__((ext_vector_type(4))) _Float16 h4;
typedef __attribute__((ext_vector_type(4))) float f4;

// ---------------- kernel 0: transpose+convert 6 weight matrices to f16 [q][col][k]
// q order: 0=lgate 1=left 2=rgate 3=right 4=gate 5=out
__global__ void prep_weights(const float* __restrict__ w0, const float* __restrict__ w1,
                             const float* __restrict__ w2, const float* __restrict__ w3,
                             const float* __restrict__ w4, const float* __restrict__ w5,
                             _Float16* __restrict__ wT)
{
    int q = blockIdx.x;
    const float* w = q==0?w0: q==1?w1: q==2?w2: q==3?w3: q==4?w4: w5;
    _Float16* dst = wT + q*Cc*Cc;
    for (int idx = threadIdx.x; idx < Cc*Cc; idx += blockDim.x) {
        int k = idx >> 7, c = idx & 127;
        dst[c*Cc + k] = (_Float16)w[idx];   // coalesced read, scattered 2B write (tiny)
    }
}

// ---------------- kernel 1: LN(z) + 5 projections, write a_t/b_t/g_t (channel-major f16)
__global__ __launch_bounds__(256)
void ln_proj(const float* __restrict__ z, const float* __restrict__ mask,
             const float* __restrict__ lnsc, const float* __restrict__ lnbs,
             const _Float16* __restrict__ wT,
             const float* __restrict__ b_lgate, const float* __restrict__ b_left,
             const float* __restrict__ b_rgate, const float* __restrict__ b_right,
             const float* __restrict__ b_gate,
             _Float16* __restrict__ a_t, _Float16* __restrict__ b_t,
             _Float16* __restrict__ g_t)
{
    __shared__ _Float16 zl[128][136];   // stride 136: 16B-aligned rows, 2-way (free) frag reads
    __shared__ float ml[128];
    const int r0 = blockIdx.x * 128;
    const int t = threadIdx.x;

    { // phase A: layernorm 128 rows, 2 threads/row
        const int r = t >> 1, h = t & 1;
        const float* zp = z + (size_t)(r0 + r)*Cc + h*64;
        float vals[64];
        float s = 0.f, s2 = 0.f;
#pragma unroll
        for (int j = 0; j < 64; j += 4) {
            float4 v = *(const float4*)(zp + j);
            vals[j]=v.x; vals[j+1]=v.y; vals[j+2]=v.z; vals[j+3]=v.w;
            s  += (v.x+v.y)+(v.z+v.w);
            s2 += (v.x*v.x+v.y*v.y)+(v.z*v.z+v.w*v.w);
        }
        s  += __shfl_xor(s, 1);
        s2 += __shfl_xor(s2, 1);
        const float mean = s * (1.f/128.f);
        const float rstd = rsqrtf(s2*(1.f/128.f) - mean*mean + 1e-5f);
        if (h == 0) ml[r] = mask[r0 + r];
#pragma unroll
        for (int j = 0; j < 64; j += 4) {
            float4 sc = *(const float4*)(lnsc + h*64 + j);
            float4 bs = *(const float4*)(lnbs + h*64 + j);
            h4 o;
            o[0] = (_Float16)((vals[j+0]-mean)*rstd*sc.x + bs.x);
            o[1] = (_Float16)((vals[j+1]-mean)*rstd*sc.y + bs.y);
            o[2] = (_Float16)((vals[j+2]-mean)*rstd*sc.z + bs.z);
            o[3] = (_Float16)((vals[j+3]-mean)*rstd*sc.w + bs.w);
            *(h4*)&zl[r][h*64+j] = o;
        }
    }
    __syncthreads();

    const int w = t >> 6, l = t & 63;
    const int l15 = l & 15, l4 = l >> 4;
    const int rowb0 = w*32 + l4*4;
    f4 acc[2][8];
    h4 sig[2][8];          // sigmoid(gate) kept in registers between q pairs
    const f4 zv = {0.f, 0.f, 0.f, 0.f};

    for (int q = 0; q < 5; ++q) {
        const _Float16* wq = wT + q*Cc*Cc;
        const float* bias = (q==0)?b_lgate : (q==1)?b_left : (q==2)?b_rgate : (q==3)?b_right : b_gate;
#pragma unroll
        for (int mt = 0; mt < 2; ++mt)
#pragma unroll
            for (int nt = 0; nt < 8; ++nt) acc[mt][nt] = zv;
#pragma unroll
        for (int kt = 0; kt < 4; ++kt) {
            const int kb = kt*32 + l4*8;
            h8 aF[2], bF[8];
#pragma unroll
            for (int mt = 0; mt < 2; ++mt)
                aF[mt] = *(const h8*)&zl[w*32 + mt*16 + l15][kb];
#pragma unroll
            for (int nt = 0; nt < 8; ++nt)
                bF[nt] = *(const h8*)&wq[(size_t)(nt*16 + l15)*Cc + kb];
#pragma unroll
            for (int mt = 0; mt < 2; ++mt)
#pragma unroll
                for (int nt = 0; nt < 8; ++nt)
                    acc[mt][nt] = __builtin_amdgcn_mfma_f32_16x16x32_f16(aF[mt], bF[nt], acc[mt][nt], 0, 0, 0);
        }
        if (q == 0 || q == 2) {          // gate projections -> sigmoid, keep in regs
#pragma unroll
            for (int mt = 0; mt < 2; ++mt)
#pragma unroll
                for (int nt = 0; nt < 8; ++nt) {
                    const float bv = bias[nt*16 + l15];
                    h4 o;
#pragma unroll
                    for (int v = 0; v < 4; ++v) {
                        float x = acc[mt][nt][v] + bv;
                        o[v] = (_Float16)(1.f/(1.f + __expf(-x)));
                    }
                    sig[mt][nt] = o;
                }
        } else if (q == 1 || q == 3) {   // linear projections -> combine, store channel-major
            _Float16* dst = (q == 1) ? a_t : b_t;
#pragma unroll
            for (int mt = 0; mt < 2; ++mt) {
                const int rowb = rowb0 + mt*16;
                const float4 mv = *(const float4*)&ml[rowb];
#pragma unroll
                for (int nt = 0; nt < 8; ++nt) {
                    const int col = nt*16 + l15;
                    const float bv = bias[col];
                    h4 sg4 = sig[mt][nt];
                    h4 o;
                    o[0] = (_Float16)(mv.x * (float)sg4[0] * (acc[mt][nt][0] + bv));
                    o[1] = (_Float16)(mv.y * (float)sg4[1] * (acc[mt][nt][1] + bv));
                    o[2] = (_Float16)(mv.z * (float)sg4[2] * (acc[mt][nt][2] + bv));
                    o[3] = (_Float16)(mv.w * (float)sg4[3] * (acc[mt][nt][3] + bv));
                    *(h4*)(dst + (size_t)col*NRr + r0 + rowb) = o;   // 4 consecutive rows -> 8B store
                }
            }
        } else {                          // q==4: output gate g
#pragma unroll
            for (int mt = 0; mt < 2; ++mt) {
                const int rowb = rowb0 + mt*16;
#pragma unroll
                for (int nt = 0; nt < 8; ++nt) {
                    const int col = nt*16 + l15;
                    const float bv = bias[col];
                    h4 o;
#pragma unroll
                    for (int v = 0; v < 4; ++v) {
                        float x = acc[mt][nt][v] + bv;
                        o[v] = (_Float16)(1.f/(1.f + __expf(-x)));
                    }
                    *(h4*)(g_t + (size_t)col*NRr + r0 + rowb) = o;
                }
            }
        }
    }
}

// ---------------- kernel 2: per-channel 128x128x512 GEMM  X_c = A_c * B_c^T
// global_load_lds(16B) staging with XOR-swizzled LDS (swizzle applied on the global fetch side)
__global__ __launch_bounds__(256)
void einsum_k(const _Float16* __restrict__ a_t, const _Float16* __restrict__ b_t,
              _Float16* __restrict__ x_t)
{
    __shared__ _Float16 At[8192];   // 128 rows x 64 k, swizzled in 16B chunks
    __shared__ _Float16 Bt[8192];
    const int bid = blockIdx.x;
    const int c = bid >> 4, it = (bid >> 2) & 3, jt = bid & 3;
    const int t = threadIdx.x, w = t >> 6, l = t & 63;
    const int l15 = l & 15, l4 = l >> 4;
    const int rl = l >> 3;             // row within 8-row chunk
    const int kcs = (l & 7) ^ rl;      // swizzled k-chunk this lane fetches
    const _Float16* Ag = a_t + (size_t)c*NRr + (size_t)it*128*512;
    const _Float16* Bg = b_t + (size_t)c*NRr + (size_t)jt*128*512;
    const _Float16* gmat = (w < 2) ? Ag : Bg;
    _Float16* lmat = (w < 2) ? (_Float16*)At : (_Float16*)Bt;
    const int chb = (w & 1) * 8;       // waves 0,2 -> chunks 0..7 ; waves 1,3 -> 8..15

    f4 acc[2][8];
    const f4 zv = {0.f,0.f,0.f,0.f};
#pragma unroll
    for (int mt = 0; mt < 2; ++mt)
#pragma unroll
        for (int nt = 0; nt < 8; ++nt) acc[mt][nt] = zv;

    for (int kb = 0; kb < 8; ++kb) {
        const int k0 = kb*64;
#pragma unroll
        for (int s = 0; s < 8; ++s) {
            const int chm = chb + s;               // chunk within the matrix (0..15)
            const int row = chm*8 + rl;
            const _Float16* gp = gmat + (size_t)row*512 + k0 + kcs*8;
            __builtin_amdgcn_global_load_lds(
                (const __attribute__((address_space(1))) unsigned int*)gp,
                (__attribute__((address_space(3))) unsigned int*)&lmat[chm*512],
                16, 0, 0);
        }
        __syncthreads();
#pragma unroll
        for (int kt = 0; kt < 2; ++kt) {
            const int kc = kt*4 + l4;
            h8 aF[2], bF[8];
#pragma unroll
            for (int mt = 0; mt < 2; ++mt) {
                const int r = w*32 + mt*16 + l15;
                aF[mt] = *(const h8*)&At[(r*8 + (kc ^ (r & 7)))*8];
            }
#pragma unroll
            for (int nt = 0; nt < 8; ++nt) {
                const int r = nt*16 + l15;
                bF[nt] = *(const h8*)&Bt[(r*8 + (kc ^ (r & 7)))*8];
            }
#pragma unroll
            for (int mt = 0; mt < 2; ++mt)
#pragma unroll
                for (int nt = 0; nt < 8; ++nt)
                    acc[mt][nt] = __builtin_amdgcn_mfma_f32_16x16x32_f16(aF[mt], bF[nt], acc[mt][nt], 0, 0, 0);
        }
        __syncthreads();
    }
    // epilogue: x_t[c][i*512 + j] f16 (L2 write-combining assembles full lines)
    _Float16* xp = x_t + (size_t)c*NRr;
    const int ib = it*128 + w*32 + l4*4;
    const int jb = jt*128 + l15;
#pragma unroll
    for (int mt = 0; mt < 2; ++mt)
#pragma unroll
        for (int nt = 0; nt < 8; ++nt) {
            const int i0 = ib + mt*16;
            const int j = jb + nt*16;
#pragma unroll
            for (int v = 0; v < 4; ++v)
                xp[(size_t)(i0 + v)*512 + j] = (_Float16)acc[mt][nt][v];
        }
}

// ---------------- kernel 3a: LN stats over channels
__global__ void stats_k(const _Float16* __restrict__ x_t, float* __restrict__ mu, float* __restrict__ rstd)
{
    const int r = blockIdx.x*512 + threadIdx.x*2;
    float s0=0.f, s1=0.f, q0=0.f, q1=0.f;
    for (int ci = 0; ci < Cc; ++ci) {
        union { unsigned int u; _Float16 h[2]; } cv;
        cv.u = *(const unsigned int*)(x_t + (size_t)ci*NRr + r);
        float v0 = (float)cv.h[0], v1 = (float)cv.h[1];
        s0 += v0; q0 += v0*v0;
        s1 += v1; q1 += v1*v1;
    }
    const float m0 = s0*(1.f/128.f), m1 = s1*(1.f/128.f);
    mu[r]   = m0;  rstd[r]   = rsqrtf(q0*(1.f/128.f) - m0*m0 + 1e-5f);
    mu[r+1] = m1;  rstd[r+1] = rsqrtf(q1*(1.f/128.f) - m1*m1 + 1e-5f);
}

// ---------------- kernel 3b: LN-on-the-fly + @w_out + b_out, times g
__global__ __launch_bounds__(256)
void out_proj(const _Float16* __restrict__ x_t, const float* __restrict__ mu, const float* __restrict__ rstd,
              const float* __restrict__ lnsc, const float* __restrict__ lnbs,
              const _Float16* __restrict__ wOutT, const float* __restrict__ b_out,
              const _Float16* __restrict__ g_t, float* __restrict__ out)
{
    __shared__ _Float16 xn[128][136];
    const int r0 = blockIdx.x * 128;
    const int t = threadIdx.x;
    { // phase A: gather + normalize block's 128 (i,j) rows into LDS (A-layout [row][k=c])
        const int cc = t >> 1, h = t & 1;
        const _Float16* xp = x_t + (size_t)cc*NRr + r0 + h*64;
        const float sc = lnsc[cc], bs = lnbs[cc];
#pragma unroll
        for (int j = 0; j < 64; j += 2) {
            union { unsigned int u; _Float16 h2[2]; } cv;
            cv.u = *(const unsigned int*)(xp + j);
            const int r = h*64 + j;
            float2 m2  = *(const float2*)(mu + r0 + r);
            float2 rs2 = *(const float2*)(rstd + r0 + r);
            xn[r][cc]   = (_Float16)(((float)cv.h2[0] - m2.x)*rs2.x*sc + bs);
            xn[r+1][cc] = (_Float16)(((float)cv.h2[1] - m2.y)*rs2.y*sc + bs);
        }
    }
    __syncthreads();
    const int w = t >> 6, l = t & 63;
    const int l15 = l & 15, l4 = l >> 4;
    f4 acc[2][8];
    const f4 zv = {0.f,0.f,0.f,0.f};
#pragma unroll
    for (int mt = 0; mt < 2; ++mt)
#pragma unroll
        for (int nt = 0; nt < 8; ++nt) acc[mt][nt] = zv;
#pragma unroll
    for (int kt = 0; kt < 4; ++kt) {
        const int kb = kt*32 + l4*8;
        h8 aF[2], bF[8];
#pragma unroll
        for (int mt = 0; mt < 2; ++mt)
            aF[mt] = *(const h8*)&xn[w*32 + mt*16 + l15][kb];
#pragma unroll
        for (int nt = 0; nt < 8; ++nt)
            bF[nt] = *(const h8*)&wOutT[(size_t)(nt*16 + l15)*Cc + kb];
#pragma unroll
        for (int mt = 0; mt < 2; ++mt)
#pragma unroll
            for (int nt = 0; nt < 8; ++nt)
                acc[mt][nt] = __builtin_amdgcn_mfma_f32_16x16x32_f16(aF[mt], bF[nt], acc[mt][nt], 0, 0, 0);
    }
    const int rowb0 = w*32 + l4*4;
#pragma unroll
    for (int mt = 0; mt < 2; ++mt) {
        const int rowb = rowb0 + mt*16;
#pragma unroll
        for (int nt = 0; nt < 8; ++nt) {
            const int col = nt*16 + l15;
            const float bv = b_out[col];
            h4 gv = *(const h4*)(g_t + (size_t)col*NRr + r0 + rowb);
#pragma unroll
            for (int v = 0; v < 4; ++v)
                out[(size_t)(r0 + rowb + v)*Cc + col] = (acc[mt][nt][v] + bv) * (float)gv[v];
        }
    }
}

extern "C" void kernel_launch(void* const* d_in, const int* in_sizes, int n_in,
                              void* d_out, int out_size, void* d_ws, size_t ws_size,
                              hipStream_t stream)
{
    (void)in_sizes; (void)n_in; (void)out_size; (void)ws_size;
    const float* z        = (const float*)d_in[0];
    const float* mask     = (const float*)d_in[1];
    const float* ln_in_s  = (const float*)d_in[2];
    const float* ln_in_b  = (const float*)d_in[3];
    const float* w_left   = (const float*)d_in[4];
    const float* b_left   = (const float*)d_in[5];
    const float* w_right  = (const float*)d_in[6];
    const float* b_right  = (const float*)d_in[7];
    const float* w_lgate  = (const float*)d_in[8];
    const float* b_lgate  = (const float*)d_in[9];
    const float* w_rgate  = (const float*)d_in[10];
    const float* b_rgate  = (const float*)d_in[11];
    const float* ln_out_s = (const float*)d_in[12];
    const float* ln_out_b = (const float*)d_in[13];
    const float* w_out    = (const float*)d_in[14];
    const float* b_out    = (const float*)d_in[15];
    const float* w_gate   = (const float*)d_in[16];
    const float* b_gate   = (const float*)d_in[17];
    float* out = (float*)d_out;

    char* ws = (char*)d_ws;
    const size_t WSZ = 196608;            // 6 * 128*128 * 2B
    const size_t PL  = 67108864;          // 128 * 262144 * 2B
    _Float16* wT  = (_Float16*)(ws);
    _Float16* a_t = (_Float16*)(ws + WSZ);
    _Float16* b_t = (_Float16*)(ws + WSZ + PL);
    _Float16* g_t = (_Float16*)(ws + WSZ + 2*PL);
    _Float16* x_t = (_Float16*)(ws + WSZ + 3*PL);
    float* mu     = (float*)(ws + WSZ + 4*PL);
    float* rstd   = (float*)(ws + WSZ + 4*PL + 1048576);

    prep_weights<<<6, 256, 0, stream>>>(w_lgate, w_left, w_rgate, w_right, w_gate, w_out, wT);
    ln_proj<<<2048, 256, 0, stream>>>(z, mask, ln_in_s, ln_in_b, wT,
                                      b_lgate, b_left, b_rgate, b_right, b_gate,
                                      a_t, b_t, g_t);
    einsum_k<<<2048, 256, 0, stream>>>(a_t, b_t, x_t);
    stats_k<<<512, 256, 0, stream>>>(x_t, mu, rstd);
    out_proj<<<2048, 256, 0, stream>>>(x_t, mu, rstd, ln_out_s, ln_out_b,
                                       wT + 5*Cc*Cc, b_out, g_t, out);
}

// Round 2
// 604.223 us; speedup vs baseline: 1.2694x; 1.2694x over previous
//
#include <hip/hip_runtime.h>

#define Nn 512
#define Cc 128
#define NRr (Nn*Nn)

typedef __attribute__((ext_vector_type(8))) _Float16 h8;
typedef __attribute__((ext_vector_type(4))) _Float16 h4;
typedef __attribute__((ext_vector_type(4))) float f4;

// ---------------- kernel 0: transpose+convert 6 weight matrices to f16 [q][col][k]
// q order: 0=lgate 1=left 2=rgate 3=right 4=gate 5=out
__global__ void prep_weights(const float* __restrict__ w0, const float* __restrict__ w1,
                             const float* __restrict__ w2, const float* __restrict__ w3,
                             const float* __restrict__ w4, const float* __restrict__ w5,
                             _Float16* __restrict__ wT)
{
    int q = blockIdx.x;
    const float* w = q==0?w0: q==1?w1: q==2?w2: q==3?w3: q==4?w4: w5;
    _Float16* dst = wT + q*Cc*Cc;
    for (int idx = threadIdx.x; idx < Cc*Cc; idx += blockDim.x) {
        int k = idx >> 7, c = idx & 127;
        dst[c*Cc + k] = (_Float16)w[idx];
    }
}

// Stage one 128x128 f16 matrix (row-major, 256B rows) into LDS with 16B-chunk XOR swizzle.
// LDS slot s of row r holds global chunk (s ^ (r&15)). dest = waveBase + lane*16 (HW rule).
__device__ __forceinline__ void stage_w(const _Float16* __restrict__ wq, _Float16* wl,
                                        int w, int l)
{
#pragma unroll
    for (int s = 0; s < 8; ++s) {
        const int rowb = s*16 + w*4;                 // wave-uniform base row
        const int row  = rowb + (l >> 4);
        const int gch  = (l & 15) ^ (row & 15);
        const _Float16* gp = wq + row*128 + gch*8;
        __builtin_amdgcn_global_load_lds(
            (const __attribute__((address_space(1))) unsigned int*)gp,
            (__attribute__((address_space(3))) unsigned int*)&wl[rowb*128],
            16, 0, 0);
    }
}

// ---------------- kernel 1: LN(z) + 5 projections
// a_t/b_t channel-major f16 [c][r];  g_r row-major f16 [r][c]
__global__ __launch_bounds__(256)
void ln_proj(const float* __restrict__ z, const float* __restrict__ mask,
             const float* __restrict__ lnsc, const float* __restrict__ lnbs,
             const _Float16* __restrict__ wT,
             const float* __restrict__ b_lgate, const float* __restrict__ b_left,
             const float* __restrict__ b_rgate, const float* __restrict__ b_right,
             const float* __restrict__ b_gate,
             _Float16* __restrict__ a_t, _Float16* __restrict__ b_t,
             _Float16* __restrict__ g_r)
{
    __shared__ __align__(16) _Float16 zl[16384];   // [r][c] swizzled 16B chunks
    __shared__ __align__(16) _Float16 wl[16384];   // staged weight, swizzled
    const int r0 = blockIdx.x * 128;
    const int t = threadIdx.x;
    const int w = t >> 6, l = t & 63;

    { // phase A: coalesced LN. wave = 2 contiguous rows per iteration.
        const int grp = t >> 5, lane32 = t & 31;
        const float4 sc4 = *(const float4*)(lnsc + lane32*4);
        const float4 bs4 = *(const float4*)(lnbs + lane32*4);
        const int chunk = lane32 >> 1, sub = (lane32 & 1) * 4;
#pragma unroll
        for (int i = 0; i < 16; ++i) {
            const int r = i*8 + grp;
            float4 v = *(const float4*)(z + (size_t)(r0 + r)*128 + lane32*4);
            float s  = (v.x+v.y)+(v.z+v.w);
            float s2 = (v.x*v.x+v.y*v.y)+(v.z*v.z+v.w*v.w);
#pragma unroll
            for (int m = 1; m < 32; m <<= 1) { s += __shfl_xor(s, m); s2 += __shfl_xor(s2, m); }
            const float mean = s * (1.f/128.f);
            const float rstd = rsqrtf(s2*(1.f/128.f) - mean*mean + 1e-5f);
            h4 o;
            o[0] = (_Float16)((v.x-mean)*rstd*sc4.x + bs4.x);
            o[1] = (_Float16)((v.y-mean)*rstd*sc4.y + bs4.y);
            o[2] = (_Float16)((v.z-mean)*rstd*sc4.z + bs4.z);
            o[3] = (_Float16)((v.w-mean)*rstd*sc4.w + bs4.w);
            *(h4*)&zl[r*128 + ((chunk ^ (r & 15)) << 3) + sub] = o;
        }
    }

    const int l15 = l & 15, l4 = l >> 4;
    const int rowb0 = w*32 + l4*4;
    // mask rows for this lane (used q==1,3), loaded once from global
    const float4 mv0 = *(const float4*)(mask + r0 + rowb0);
    const float4 mv1 = *(const float4*)(mask + r0 + rowb0 + 16);

    f4 acc[2][8];
    h4 sig[2][8];
    const f4 zv = {0.f, 0.f, 0.f, 0.f};

    stage_w(wT, wl, w, l);          // q=0 staged before first barrier
    __syncthreads();                 // zl visible + staging drained

    for (int q = 0; q < 5; ++q) {
        const float* bias = (q==0)?b_lgate : (q==1)?b_left : (q==2)?b_rgate : (q==3)?b_right : b_gate;
#pragma unroll
        for (int mt = 0; mt < 2; ++mt)
#pragma unroll
            for (int nt = 0; nt < 8; ++nt) acc[mt][nt] = zv;
#pragma unroll
        for (int kt = 0; kt < 4; ++kt) {
            const int ch = kt*4 + l4;
            h8 aF[2], bF[8];
#pragma unroll
            for (int mt = 0; mt < 2; ++mt) {
                const int row = w*32 + mt*16 + l15;
                aF[mt] = *(const h8*)&zl[row*128 + ((ch ^ l15) << 3)];
            }
#pragma unroll
            for (int nt = 0; nt < 8; ++nt) {
                const int row = nt*16 + l15;
                bF[nt] = *(const h8*)&wl[row*128 + ((ch ^ l15) << 3)];
            }
#pragma unroll
            for (int mt = 0; mt < 2; ++mt)
#pragma unroll
                for (int nt = 0; nt < 8; ++nt)
                    acc[mt][nt] = __builtin_amdgcn_mfma_f32_16x16x32_f16(aF[mt], bF[nt], acc[mt][nt], 0, 0, 0);
        }
        // pre-stage next q's weight (overwrite wl) behind a barrier pair
        if (q < 4) {
            __syncthreads();                        // all frag reads of wl done
            stage_w(wT + (q+1)*Cc*Cc, wl, w, l);
            __syncthreads();
        }

        if (q == 0 || q == 2) {          // gate projections -> sigmoid, keep in regs
#pragma unroll
            for (int mt = 0; mt < 2; ++mt)
#pragma unroll
                for (int nt = 0; nt < 8; ++nt) {
                    const float bv = bias[nt*16 + l15];
                    h4 o;
#pragma unroll
                    for (int v = 0; v < 4; ++v) {
                        float x = acc[mt][nt][v] + bv;
                        o[v] = (_Float16)(1.f/(1.f + __expf(-x)));
                    }
                    sig[mt][nt] = o;
                }
        } else if (q == 1 || q == 3) {   // combine with sigmoid+mask, store channel-major
            _Float16* dst = (q == 1) ? a_t : b_t;
#pragma unroll
            for (int mt = 0; mt < 2; ++mt) {
                const int rowb = rowb0 + mt*16;
                const float4 mv = (mt == 0) ? mv0 : mv1;
#pragma unroll
                for (int nt = 0; nt < 8; ++nt) {
                    const int col = nt*16 + l15;
                    const float bv = bias[col];
                    h4 sg4 = sig[mt][nt];
                    h4 o;
                    o[0] = (_Float16)(mv.x * (float)sg4[0] * (acc[mt][nt][0] + bv));
                    o[1] = (_Float16)(mv.y * (float)sg4[1] * (acc[mt][nt][1] + bv));
                    o[2] = (_Float16)(mv.z * (float)sg4[2] * (acc[mt][nt][2] + bv));
                    o[3] = (_Float16)(mv.w * (float)sg4[3] * (acc[mt][nt][3] + bv));
                    *(h4*)(dst + (size_t)col*NRr + r0 + rowb) = o;
                }
            }
        } else {                          // q==4: output gate g, ROW-major
#pragma unroll
            for (int mt = 0; mt < 2; ++mt) {
                const int rowb = rowb0 + mt*16;
#pragma unroll
                for (int nt = 0; nt < 8; ++nt) {
                    const int col = nt*16 + l15;
                    const float bv = bias[col];
#pragma unroll
                    for (int v = 0; v < 4; ++v) {
                        float x = acc[mt][nt][v] + bv;
                        g_r[(size_t)(r0 + rowb + v)*Cc + col] = (_Float16)(1.f/(1.f + __expf(-x)));
                    }
                }
            }
        }
    }
}

// ---------------- kernel 2: per-channel 128x128x512 GEMM  X_c = A_c * B_c^T (unchanged)
__global__ __launch_bounds__(256)
void einsum_k(const _Float16* __restrict__ a_t, const _Float16* __restrict__ b_t,
              _Float16* __restrict__ x_t)
{
    __shared__ __align__(16) _Float16 At[8192];
    __shared__ __align__(16) _Float16 Bt[8192];
    const int bid = blockIdx.x;
    const int c = bid >> 4, it = (bid >> 2) & 3, jt = bid & 3;
    const int t = threadIdx.x, w = t >> 6, l = t & 63;
    const int l15 = l & 15, l4 = l >> 4;
    const int rl = l >> 3;
    const int kcs = (l & 7) ^ rl;
    const _Float16* Ag = a_t + (size_t)c*NRr + (size_t)it*128*512;
    const _Float16* Bg = b_t + (size_t)c*NRr + (size_t)jt*128*512;
    const _Float16* gmat = (w < 2) ? Ag : Bg;
    _Float16* lmat = (w < 2) ? (_Float16*)At : (_Float16*)Bt;
    const int chb = (w & 1) * 8;

    f4 acc[2][8];
    const f4 zv = {0.f,0.f,0.f,0.f};
#pragma unroll
    for (int mt = 0; mt < 2; ++mt)
#pragma unroll
        for (int nt = 0; nt < 8; ++nt) acc[mt][nt] = zv;

    for (int kb = 0; kb < 8; ++kb) {
        const int k0 = kb*64;
#pragma unroll
        for (int s = 0; s < 8; ++s) {
            const int chm = chb + s;
            const int row = chm*8 + rl;
            const _Float16* gp = gmat + (size_t)row*512 + k0 + kcs*8;
            __builtin_amdgcn_global_load_lds(
                (const __attribute__((address_space(1))) unsigned int*)gp,
                (__attribute__((address_space(3))) unsigned int*)&lmat[chm*512],
                16, 0, 0);
        }
        __syncthreads();
#pragma unroll
        for (int kt = 0; kt < 2; ++kt) {
            const int kc = kt*4 + l4;
            h8 aF[2], bF[8];
#pragma unroll
            for (int mt = 0; mt < 2; ++mt) {
                const int r = w*32 + mt*16 + l15;
                aF[mt] = *(const h8*)&At[(r*8 + (kc ^ (r & 7)))*8];
            }
#pragma unroll
            for (int nt = 0; nt < 8; ++nt) {
                const int r = nt*16 + l15;
                bF[nt] = *(const h8*)&Bt[(r*8 + (kc ^ (r & 7)))*8];
            }
#pragma unroll
            for (int mt = 0; mt < 2; ++mt)
#pragma unroll
                for (int nt = 0; nt < 8; ++nt)
                    acc[mt][nt] = __builtin_amdgcn_mfma_f32_16x16x32_f16(aF[mt], bF[nt], acc[mt][nt], 0, 0, 0);
        }
        __syncthreads();
    }
    _Float16* xp = x_t + (size_t)c*NRr;
    const int ib = it*128 + w*32 + l4*4;
    const int jb = jt*128 + l15;
#pragma unroll
    for (int mt = 0; mt < 2; ++mt)
#pragma unroll
        for (int nt = 0; nt < 8; ++nt) {
            const int i0 = ib + mt*16;
            const int j = jb + nt*16;
#pragma unroll
            for (int v = 0; v < 4; ++v)
                xp[(size_t)(i0 + v)*512 + j] = (_Float16)acc[mt][nt][v];
        }
}

// ---------------- kernel 2.5: transpose x_t [c][r] -> x_r [r][c] + fused LN stats per row
__global__ __launch_bounds__(256)
void transpose_x(const _Float16* __restrict__ xt, _Float16* __restrict__ xr,
                 float* __restrict__ mu, float* __restrict__ rstd)
{
    __shared__ __align__(16) _Float16 tl[128*130];   // [c][r], per-c stride 130
    const int r0 = blockIdx.x * 128;
    const int t = threadIdx.x;
    // load: 8 iters, per-instr 4 contiguous 256B channel segments
#pragma unroll
    for (int it = 0; it < 8; ++it) {
        const int c = it*16 + (t >> 4);
        const int rchunk = t & 15;
        h8 v = *(const h8*)(xt + (size_t)c*NRr + r0 + rchunk*8);
        *(h8*)&tl[c*130 + rchunk*8] = v;
    }
    __syncthreads();
    // store: thread covers rows {t>>2, t>>2+64} x 4 c-chunks; full-line global stores
#pragma unroll
    for (int rh = 0; rh < 2; ++rh) {
        const int r = (t >> 2) + 64*rh;
        float s = 0.f, s2 = 0.f;
#pragma unroll
        for (int cl = 0; cl < 4; ++cl) {
            const int cchunk = (t & 3) + 4*cl;
            union { _Float16 h[8]; h8 v; } u;
#pragma unroll
            for (int j = 0; j < 8; ++j) {
                _Float16 hv = tl[(cchunk*8 + j)*130 + r];
                u.h[j] = hv;
                float f = (float)hv;
                s += f; s2 += f*f;
            }
            *(h8*)(xr + (size_t)(r0 + r)*Cc + cchunk*8) = u.v;
        }
        s  += __shfl_xor(s, 1);  s  += __shfl_xor(s, 2);
        s2 += __shfl_xor(s2, 1); s2 += __shfl_xor(s2, 2);
        if ((t & 3) == 0) {
            const float m = s * (1.f/128.f);
            mu[r0 + r] = m;
            rstd[r0 + r] = rsqrtf(s2*(1.f/128.f) - m*m + 1e-5f);
        }
    }
}

// ---------------- kernel 3: LN(x) @ w_out + b_out, times g
__global__ __launch_bounds__(256)
void out_proj(const _Float16* __restrict__ xr, const float* __restrict__ mu, const float* __restrict__ rstd,
              const float* __restrict__ lnsc, const float* __restrict__ lnbs,
              const _Float16* __restrict__ wOutT, const float* __restrict__ b_out,
              const _Float16* __restrict__ g_r, float* __restrict__ out)
{
    __shared__ __align__(16) _Float16 zl[16384];   // normalized x, swizzled
    __shared__ __align__(16) _Float16 wl[16384];
    const int r0 = blockIdx.x * 128;
    const int t = threadIdx.x;
    const int w = t >> 6, l = t & 63;

    { // phase A: coalesced normalize into LDS
        const int grp = t >> 5, lane32 = t & 31;
        const float4 sc4 = *(const float4*)(lnsc + lane32*4);
        const float4 bs4 = *(const float4*)(lnbs + lane32*4);
        const int chunk = lane32 >> 1, sub = (lane32 & 1) * 4;
#pragma unroll
        for (int i = 0; i < 16; ++i) {
            const int r = i*8 + grp;
            h4 xv = *(const h4*)(xr + (size_t)(r0 + r)*Cc + lane32*4);
            const float m = mu[r0 + r], rs = rstd[r0 + r];
            h4 o;
            o[0] = (_Float16)(((float)xv[0]-m)*rs*sc4.x + bs4.x);
            o[1] = (_Float16)(((float)xv[1]-m)*rs*sc4.y + bs4.y);
            o[2] = (_Float16)(((float)xv[2]-m)*rs*sc4.z + bs4.z);
            o[3] = (_Float16)(((float)xv[3]-m)*rs*sc4.w + bs4.w);
            *(h4*)&zl[r*128 + ((chunk ^ (r & 15)) << 3) + sub] = o;
        }
    }
    stage_w(wOutT, wl, w, l);
    __syncthreads();

    const int l15 = l & 15, l4 = l >> 4;
    f4 acc[2][8];
    const f4 zv = {0.f,0.f,0.f,0.f};
#pragma unroll
    for (int mt = 0; mt < 2; ++mt)
#pragma unroll
        for (int nt = 0; nt < 8; ++nt) acc[mt][nt] = zv;
#pragma unroll
    for (int kt = 0; kt < 4; ++kt) {
        const int ch = kt*4 + l4;
        h8 aF[2], bF[8];
#pragma unroll
        for (int mt = 0; mt < 2; ++mt) {
            const int row = w*32 + mt*16 + l15;
            aF[mt] = *(const h8*)&zl[row*128 + ((ch ^ l15) << 3)];
        }
#pragma unroll
        for (int nt = 0; nt < 8; ++nt) {
            const int row = nt*16 + l15;
            bF[nt] = *(const h8*)&wl[row*128 + ((ch ^ l15) << 3)];
        }
#pragma unroll
        for (int mt = 0; mt < 2; ++mt)
#pragma unroll
            for (int nt = 0; nt < 8; ++nt)
                acc[mt][nt] = __builtin_amdgcn_mfma_f32_16x16x32_f16(aF[mt], bF[nt], acc[mt][nt], 0, 0, 0);
    }
    const int rowb0 = w*32 + l4*4;
#pragma unroll
    for (int mt = 0; mt < 2; ++mt) {
        const int rowb = rowb0 + mt*16;
#pragma unroll
        for (int nt = 0; nt < 8; ++nt) {
            const int col = nt*16 + l15;
            const float bv = b_out[col];
#pragma unroll
            for (int v = 0; v < 4; ++v) {
                const float g = (float)g_r[(size_t)(r0 + rowb + v)*Cc + col];
                out[(size_t)(r0 + rowb + v)*Cc + col] = (acc[mt][nt][v] + bv) * g;
            }
        }
    }
}

extern "C" void kernel_launch(void* const* d_in, const int* in_sizes, int n_in,
                              void* d_out, int out_size, void* d_ws, size_t ws_size,
                              hipStream_t stream)
{
    (void)in_sizes; (void)n_in; (void)out_size; (void)ws_size;
    const float* z        = (const float*)d_in[0];
    const float* mask     = (const float*)d_in[1];
    const float* ln_in_s  = (const float*)d_in[2];
    const float* ln_in_b  = (const float*)d_in[3];
    const float* w_left   = (const float*)d_in[4];
    const float* b_left   = (const float*)d_in[5];
    const float* w_right  = (const float*)d_in[6];
    const float* b_right  = (const float*)d_in[7];
    const float* w_lgate  = (const float*)d_in[8];
    const float* b_lgate  = (const float*)d_in[9];
    const float* w_rgate  = (const float*)d_in[10];
    const float* b_rgate  = (const float*)d_in[11];
    const float* ln_out_s = (const float*)d_in[12];
    const float* ln_out_b = (const float*)d_in[13];
    const float* w_out    = (const float*)d_in[14];
    const float* b_out    = (const float*)d_in[15];
    const float* w_gate   = (const float*)d_in[16];
    const float* b_gate   = (const float*)d_in[17];
    float* out = (float*)d_out;

    char* ws = (char*)d_ws;
    const size_t WSZ = 196608;            // 6 * 128*128 * 2B
    const size_t PL  = 67108864;          // 128 * 262144 * 2B
    _Float16* wT  = (_Float16*)(ws);
    _Float16* a_t = (_Float16*)(ws + WSZ);
    _Float16* b_t = (_Float16*)(ws + WSZ + PL);
    _Float16* g_r = (_Float16*)(ws + WSZ + 2*PL);
    _Float16* x_t = (_Float16*)(ws + WSZ + 3*PL);
    float* mu     = (float*)(ws + WSZ + 4*PL);
    float* rstd   = (float*)(ws + WSZ + 4*PL + 1048576);
    _Float16* x_r = a_t;                  // a_t dead after einsum; reuse

    prep_weights<<<6, 256, 0, stream>>>(w_lgate, w_left, w_rgate, w_right, w_gate, w_out, wT);
    ln_proj<<<2048, 256, 0, stream>>>(z, mask, ln_in_s, ln_in_b, wT,
                                      b_lgate, b_left, b_rgate, b_right, b_gate,
                                      a_t, b_t, g_r);
    einsum_k<<<2048, 256, 0, stream>>>(a_t, b_t, x_t);
    transpose_x<<<2048, 256, 0, stream>>>(x_t, x_r, mu, rstd);
    out_proj<<<2048, 256, 0, stream>>>(x_r, mu, rstd, ln_out_s, ln_out_b,
                                       wT + 5*Cc*Cc, b_out, g_r, out);
}